// Round 13
// baseline (284.599 us; speedup 1.0000x reference)
//
#include <hip/hip_runtime.h>
#include <math.h>

#define NB    64        // graphs
#define NPER  1024      // nodes per graph
#define NTOT  65536     // total nodes
#define ETOT  1048576   // edges
#define FEAT  64
#define HID   128
#define KSEL  10
#define MAXDEG 64       // CSR slot capacity per node (max in-degree ~40)

// Pipeline (agg commuted before the weight multiply, dinv folded into gemm output):
//   A = agg(Z)             agg_k  : LDS-staged gather (dedupes neighbor reads); output
//                                   k-octet-major bf16 hi/lo Ah/Al[(k>>3)][v][k&7]
//   Z' = relu(A@W+b)*dinv  gemm_k : 64x128 MFMA tile, bf16x3 (hi*hi+hi*lo+lo*hi)
// csrpack_k: per-graph CSR in LDS atomics, SLOT-MAJOR col16[slot*NTOT+node] (wave
//   reads 64 consecutive u16 = one 128B line) + pack/part-zero tails (one dispatch).
// agg gather: R7 mapping (4 threads/node, 16 nodes/wave -> consecutive quads, bank-
//   uniform) + DEPTH-2 INDEX PIPELINE: groups j+1,j+2 in flight while consuming j,
//   hiding the ~200cy L2 index latency (R11's depth-1 = +6us; this deepens it).
// Lessons: R6 do NOT fuse gather into GEMM (17x L3 traffic @1.9TB/s). R9 no min-waves
//   launch_bounds on agg (spills -> 2x HBM). R10 per-lane random LDS quads -> 7x bank
//   conflicts; keep the R7 consecutive-quad mapping.

typedef __attribute__((ext_vector_type(8))) short bf16x8;
typedef __attribute__((ext_vector_type(4))) float f32x4;

static __device__ __forceinline__ unsigned short f2bf(float x) {   // RNE fp32->bf16
    unsigned u = __float_as_uint(x);
    return (unsigned short)((u + 0x7FFFu + ((u >> 16) & 1u)) >> 16);
}
static __device__ __forceinline__ float bf2f(unsigned short s) {
    return __uint_as_float(((unsigned)s) << 16);
}

// ------- CSR build (per-graph LDS atomics, slot-major) + pack + part-zero tail -----
__global__ __launch_bounds__(1024) void csrpack_k(const int* __restrict__ src,
                                                  const int* __restrict__ dst,
                                                  int* __restrict__ cnt,
                                                  unsigned short* __restrict__ col16,
                                                  const float* __restrict__ W0,
                                                  const float* __restrict__ W1,
                                                  const float* __restrict__ W2,
                                                  unsigned short* __restrict__ Wph,
                                                  unsigned short* __restrict__ Wpl,
                                                  float* __restrict__ part) {
    int t = threadIdx.x;
    int b = blockIdx.x;
    if (b >= NB) {
        int pb = b - NB;
        if (pb == 40) {   // zero atomicMax target (relu>=0 so 0.0f bits are the floor)
            for (int i = t; i < NB * 128; i += 1024) part[i] = 0.f;
            return;
        }
        int idx = pb * 1024 + t;          // 0..40959 covers 320*128
        if (idx >= 320 * 128) return;
        int k = idx >> 7;
        int c = idx & 127;
        float v;
        size_t mb;
        int kk;
        if (k < 64)       { kk = k;       v = W0[kk * 128 + c]; mb = 0; }
        else if (k < 192) { kk = k - 64;  v = W1[kk * 128 + c]; mb = (size_t)64 * 128; }
        else              { kk = k - 192; v = W2[kk * 128 + c]; mb = (size_t)192 * 128; }
        unsigned short h  = f2bf(v);
        unsigned short lo = f2bf(v - bf2f(h));
        size_t d = mb + ((size_t)(kk >> 3) * 128 + c) * 8 + (kk & 7);
        Wph[d] = h;
        Wpl[d] = lo;
        return;
    }
    // per-graph CSR, slot-major output
    __shared__ int lcnt[NPER];
    int g = b;
    int gbase = g << 10;
    int ebase = g * (NPER * 16);          // DEG=16, graph-contiguous edge rows
    lcnt[t] = 0;
    __syncthreads();
    const int4* ds4 = (const int4*)(dst + ebase);
    const int4* ss4 = (const int4*)(src + ebase);
#pragma unroll 1
    for (int i = 0; i < 4; ++i) {
        int e4 = i * 1024 + t;            // 4096 int4 groups cover 16384 edges
        int4 dv = ds4[e4];
        int4 sv = ss4[e4];
        int d0 = dv.x & (NPER - 1), s0 = sv.x & (NPER - 1);
        int d1 = dv.y & (NPER - 1), s1 = sv.y & (NPER - 1);
        int d2 = dv.z & (NPER - 1), s2 = sv.z & (NPER - 1);
        int d3 = dv.w & (NPER - 1), s3 = sv.w & (NPER - 1);
        int p0 = atomicAdd(&lcnt[d0], 1);
        col16[(size_t)p0 * NTOT + gbase + d0] = (unsigned short)s0;
        int p1 = atomicAdd(&lcnt[d1], 1);
        col16[(size_t)p1 * NTOT + gbase + d1] = (unsigned short)s1;
        int p2 = atomicAdd(&lcnt[d2], 1);
        col16[(size_t)p2 * NTOT + gbase + d2] = (unsigned short)s2;
        int p3 = atomicAdd(&lcnt[d3], 1);
        col16[(size_t)p3 * NTOT + gbase + d3] = (unsigned short)s3;
    }
    __syncthreads();
    cnt[gbase + t] = lcnt[t];
}

// ---------------- LDS-staged aggregation -> k-octet-major bf16 hi/lo output --------
// block=(graph g, chunk c). Z input is pre-scaled by dinv (gemm did it); x input
// (conv0) scaled here. out_v = dv * sum(staged over {v} u N(v)), split hi/lo.
// If Wf != nullptr, the LAST NB blocks instead compute glob/gproj (fused glob_k).
__global__ __launch_bounds__(1024) void agg_k(const float* __restrict__ Z,
                                              const float* __restrict__ x,
                                              const unsigned short* __restrict__ col16,
                                              const int* __restrict__ cnt,
                                              unsigned short* __restrict__ Ah,
                                              unsigned short* __restrict__ Al,
                                              int cshift,
                                              float* __restrict__ fvec,
                                              const float* __restrict__ Wf,
                                              const float* __restrict__ bfv,
                                              const float* __restrict__ W2g,
                                              float* __restrict__ gproj,
                                              const float* __restrict__ part) {
    __shared__ float4 sy4[4096];   // 64 KB
    int t = threadIdx.x;

    if (Wf && (int)blockIdx.x >= (int)gridDim.x - NB) {   // fused glob block
        float* sm = (float*)sy4;
        float* mp = sm;            // 128
        float* ps = sm + 128;      // 1024
        float* gl = sm + 128 + 1024;
        int gg = blockIdx.x - (gridDim.x - NB);
        int o = t & 127, s8 = t >> 7;       // 8 segments of 16 k each
        if (t < 128) mp[t] = part[(size_t)gg * 128 + t];
        __syncthreads();
        float p = 0.f;
#pragma unroll
        for (int q = 0; q < 16; ++q) { int k = s8 * 16 + q; p += mp[k] * Wf[(size_t)k * 128 + o]; }
        ps[t] = p;
        __syncthreads();
        if (t < 128) {
            float a = bfv[t];
#pragma unroll
            for (int q = 0; q < 8; ++q) a += ps[q * 128 + t];
            gl[t] = a;
        }
        __syncthreads();
        p = 0.f;
#pragma unroll
        for (int q = 0; q < 16; ++q) { int k = s8 * 16 + q; p += gl[k] * W2g[(size_t)(128 + k) * 128 + o]; }
        ps[t] = p;
        __syncthreads();
        if (t < 128) {
            float a = 0.f;
#pragma unroll
            for (int q = 0; q < 8; ++q) a += ps[q * 128 + t];
            gproj[(size_t)gg * 128 + t] = a;
        }
        return;
    }

    int g = blockIdx.x >> cshift;
    int c = blockIdx.x & ((1 << cshift) - 1);
    int gbase = g << 10;

    if (x) {
#pragma unroll
        for (int j = 0; j < 4; ++j) {
            int fl = j * 1024 + t;
            int v = fl >> 2, q = fl & 3;
            float dvv = rsqrtf((float)cnt[gbase + v] + 1.0f);
            float4 z = *(const float4*)&x[(size_t)(gbase + v) * FEAT + c * 16 + q * 4];
            z.x *= dvv; z.y *= dvv; z.z *= dvv; z.w *= dvv;
            sy4[fl] = z;
        }
    } else {
        const float4* Zg4 = (const float4*)(Z + ((size_t)c * NTOT + gbase) * 16);
#pragma unroll
        for (int j = 0; j < 4; ++j) sy4[j * 1024 + t] = Zg4[j * 1024 + t];
    }
    __syncthreads();

    int f4 = t & 3;
    int vl = t >> 2;                        // 0..255

#define CONSUME4(q0, q1, q2, q3)                                   \
    {                                                              \
        float4 y0 = sy4[(q0) * 4 + f4];                            \
        float4 y1 = sy4[(q1) * 4 + f4];                            \
        float4 y2 = sy4[(q2) * 4 + f4];                            \
        float4 y3 = sy4[(q3) * 4 + f4];                            \
        acc.x += (y0.x + y1.x) + (y2.x + y3.x);                    \
        acc.y += (y0.y + y1.y) + (y2.y + y3.y);                    \
        acc.z += (y0.z + y1.z) + (y2.z + y3.z);                    \
        acc.w += (y0.w + y1.w) + (y2.w + y3.w);                    \
    }

#pragma unroll 1
    for (int pass = 0; pass < 4; ++pass) {
        int v = pass * 256 + vl;
        int gv = gbase + v;
        int n = cnt[gv];
        float dv = rsqrtf((float)n + 1.0f);
        const unsigned short* ip = col16 + gv;
        float4 acc = sy4[v * 4 + f4];       // self term
        int G = n >> 2;                     // complete index groups
        int a0 = 0, a1 = 0, a2 = 0, a3 = 0;
        int b0 = 0, b1 = 0, b2 = 0, b3 = 0;
        if (G > 0) {                        // preload group 0
            a0 = ip[0];
            a1 = ip[(size_t)1 * NTOT];
            a2 = ip[(size_t)2 * NTOT];
            a3 = ip[(size_t)3 * NTOT];
        }
        if (G > 1) {                        // preload group 1
            b0 = ip[(size_t)4 * NTOT];
            b1 = ip[(size_t)5 * NTOT];
            b2 = ip[(size_t)6 * NTOT];
            b3 = ip[(size_t)7 * NTOT];
        }
#pragma unroll 1
        for (int j = 2; j < G; ++j) {       // steady state: load j while consuming j-2
            int c0 = ip[(size_t)(4 * j + 0) * NTOT];
            int c1 = ip[(size_t)(4 * j + 1) * NTOT];
            int c2 = ip[(size_t)(4 * j + 2) * NTOT];
            int c3 = ip[(size_t)(4 * j + 3) * NTOT];
            CONSUME4(a0, a1, a2, a3);
            a0 = b0; a1 = b1; a2 = b2; a3 = b3;
            b0 = c0; b1 = c1; b2 = c2; b3 = c3;
        }
        if (G > 1) {                        // drain group G-2
            CONSUME4(a0, a1, a2, a3);
            a0 = b0; a1 = b1; a2 = b2; a3 = b3;
        }
        if (G > 0) {                        // drain group G-1
            CONSUME4(a0, a1, a2, a3);
        }
        for (int i = G * 4; i < n; ++i) {   // remainder elements
            float4 ya = sy4[(int)ip[(size_t)i * NTOT] * 4 + f4];
            acc.x += ya.x; acc.y += ya.y; acc.z += ya.z; acc.w += ya.w;
        }
        acc.x *= dv; acc.y *= dv; acc.z *= dv; acc.w *= dv;
        // k-octet-major bf16 hi/lo write: plane = krow>>3, offset = krow&7 (0 or 4)
        int krow = c * 16 + f4 * 4;
        size_t ba = ((size_t)(krow >> 3) * NTOT + gv) * 8 + (krow & 7);
        ushort4 h, lo;
        h.x = f2bf(acc.x); lo.x = f2bf(acc.x - bf2f(h.x));
        h.y = f2bf(acc.y); lo.y = f2bf(acc.y - bf2f(h.y));
        h.z = f2bf(acc.z); lo.z = f2bf(acc.z - bf2f(h.z));
        h.w = f2bf(acc.w); lo.w = f2bf(acc.w - bf2f(h.w));
        *(ushort4*)&Ah[ba] = h;
        *(ushort4*)&Al[ba] = lo;
    }
#undef CONSUME4

    if (fvec && c == 0) {   // f_v = dinv_v*(dinv_v + sum dinv_s)
        __syncthreads();
        float* sdv = (float*)sy4;
        float dv = rsqrtf((float)cnt[gbase + t] + 1.0f);
        sdv[t] = dv;
        __syncthreads();
        int n = cnt[gbase + t];
        float acc = dv;
        const unsigned short* ip = col16 + gbase + t;
        for (int i = 0; i < n; ++i) acc += sdv[ip[(size_t)i * NTOT]];
        fvec[gbase + t] = dv * acc;
    }
}

// ---------------- bf16x3 MFMA GEMM: 64 rows x 128 cols per block, fused epilogue ----
// Single-shot A staging (whole K, 32 KB hi+lo, ONE barrier), B frags straight from L2
// (W small + shared by all blocks -> L2-hot broadcast; no LDS, no extra barriers).
// 4 waves; wave w owns cols w*32..w*32+31 (2x 16-col frags), all 64 rows (4x 16-row).
// A frag: row = lane&15, k-octet = lane>>4 (consistent A/B k-mapping => layout-safe).
// C/D frag (m89-verified): col = lane&15, row = (lane>>4)*4 + reg.
__global__ __launch_bounds__(256, 4) void gemm_k(const unsigned short* __restrict__ Ah,
                                                 const unsigned short* __restrict__ Al,
                                                 const unsigned short* __restrict__ Wph,
                                                 const unsigned short* __restrict__ Wpl,
                                                 const float* __restrict__ bias,
                                                 float* __restrict__ outZ,
                                                 int K,
                                                 const float* __restrict__ fvec,
                                                 const float* __restrict__ gproj,
                                                 float* __restrict__ part,
                                                 const float* __restrict__ W3,
                                                 const int* __restrict__ cnt,
                                                 float* __restrict__ zout) {
    __shared__ __align__(16) unsigned short sAh[64 * 128];   // [plane][row][8]  16 KB
    __shared__ __align__(16) unsigned short sAl[64 * 128];   // 16 KB
    __shared__ float zred[4 * 64];

    int t = threadIdx.x;
    int row0 = blockIdx.x * 64;
    int w = t >> 6;
    int l = t & 63;
    int lr = l & 15;
    int hg = l >> 4;

    f32x4 acc[4][2];
#pragma unroll
    for (int m = 0; m < 4; ++m)
#pragma unroll
        for (int n = 0; n < 2; ++n) acc[m][n] = (f32x4){0.f, 0.f, 0.f, 0.f};

    // stage ALL of A (K planes of [64 rows][8]) in one shot; per-thread nu uint4 pairs
    int nu = (K >> 3) << 6 >> 8;            // (K/8 planes * 64 rows) / 256 threads
    for (int i = 0; i < nu; ++i) {
        int u = t + i * 256;
        int p = u >> 6, r = u & 63;
        size_t src = ((size_t)p * NTOT + row0 + r) * 8;
        *(uint4*)&sAh[u * 8] = *(const uint4*)&Ah[src];
        *(uint4*)&sAl[u * 8] = *(const uint4*)&Al[src];
    }
    __syncthreads();                         // the ONLY pre-epilogue barrier

    int nk = K >> 5;
#pragma unroll 1
    for (int s = 0; s < nk; ++s) {
        int pb = s * 4 + hg;                 // this lane-group's k-plane
        bf16x8 ah[4], al[4], bh[2], bl[2];
#pragma unroll
        for (int m = 0; m < 4; ++m) {
            ah[m] = *(const bf16x8*)&sAh[(pb * 64 + m * 16 + lr) * 8];
            al[m] = *(const bf16x8*)&sAl[(pb * 64 + m * 16 + lr) * 8];
        }
#pragma unroll
        for (int n = 0; n < 2; ++n) {
            size_t wb = ((size_t)pb * 128 + w * 32 + n * 16 + lr) * 8;
            bh[n] = *(const bf16x8*)&Wph[wb];
            bl[n] = *(const bf16x8*)&Wpl[wb];
        }
#pragma unroll
        for (int m = 0; m < 4; ++m)
#pragma unroll
            for (int n = 0; n < 2; ++n) {
                acc[m][n] = __builtin_amdgcn_mfma_f32_16x16x32_bf16(ah[m], bh[n], acc[m][n], 0, 0, 0);
                acc[m][n] = __builtin_amdgcn_mfma_f32_16x16x32_bf16(al[m], bh[n], acc[m][n], 0, 0, 0);
                acc[m][n] = __builtin_amdgcn_mfma_f32_16x16x32_bf16(ah[m], bl[n], acc[m][n], 0, 0, 0);
            }
    }

    int g = row0 >> 10;
    int wc0 = w * 32;
    float bb[2], gp[2], w3c[2];
#pragma unroll
    for (int n = 0; n < 2; ++n) {
        int col = wc0 + n * 16 + lr;
        bb[n]  = bias[col];
        gp[n]  = fvec ? gproj[(size_t)g * 128 + col] : 0.f;
        w3c[n] = zout ? W3[col] : 0.f;
    }
    float fr[4][4];
    if (fvec) {
#pragma unroll
        for (int m = 0; m < 4; ++m)
#pragma unroll
            for (int r = 0; r < 4; ++r) fr[m][r] = fvec[row0 + m * 16 + hg * 4 + r];
    }
    float dvs[4][4];
    if (outZ) {
#pragma unroll
        for (int m = 0; m < 4; ++m)
#pragma unroll
            for (int r = 0; r < 4; ++r)
                dvs[m][r] = rsqrtf((float)cnt[row0 + m * 16 + hg * 4 + r] + 1.0f);
    }
    float zp[4][4];
#pragma unroll
    for (int m = 0; m < 4; ++m)
#pragma unroll
        for (int r = 0; r < 4; ++r) zp[m][r] = 0.f;
    float cmx[2] = {0.f, 0.f};

#pragma unroll
    for (int m = 0; m < 4; ++m)
#pragma unroll
        for (int n = 0; n < 2; ++n)
#pragma unroll
            for (int r = 0; r < 4; ++r) {
                float v = acc[m][n][r] + bb[n];
                if (fvec) v += fr[m][r] * gp[n];
                v = fmaxf(v, 0.f);
                if (part) cmx[n] = fmaxf(cmx[n], v);
                if (zout) zp[m][r] += v * w3c[n];
                if (outZ) {
                    int row = row0 + m * 16 + hg * 4 + r;
                    int cidx = w * 2 + n;
                    outZ[((size_t)cidx * NTOT + row) * 16 + lr] = v * dvs[m][r];
                }
            }

    if (part) {   // per-graph col-max: reduce across the wave's 64 rows, then atomicMax
#pragma unroll
        for (int n = 0; n < 2; ++n) {
            float v = cmx[n];
            v = fmaxf(v, __shfl_xor(v, 16));
            v = fmaxf(v, __shfl_xor(v, 32));
            if (hg == 0)
                atomicMax((int*)&part[(size_t)g * 128 + wc0 + n * 16 + lr],
                          __float_as_int(v));
        }
    }

    if (zout) {   // reduce row-dots across 16 col-lanes, then across 4 waves via LDS
#pragma unroll
        for (int m = 0; m < 4; ++m)
#pragma unroll
            for (int r = 0; r < 4; ++r) {
                float v = zp[m][r];
                v += __shfl_xor(v, 1);
                v += __shfl_xor(v, 2);
                v += __shfl_xor(v, 4);
                v += __shfl_xor(v, 8);
                zp[m][r] = v;
            }
        if (lr == 0) {
#pragma unroll
            for (int m = 0; m < 4; ++m)
#pragma unroll
                for (int r = 0; r < 4; ++r)
                    zred[w * 64 + m * 16 + hg * 4 + r] = zp[m][r];
        }
        __syncthreads();
        if (t < 64) {
            float sZ = zred[t] + zred[64 + t] + zred[128 + t] + zred[192 + t];
            zout[row0 + t] = sZ * rsqrtf((float)cnt[row0 + t] + 1.0f);
        }
    }
}

// ---------------- fused scalar-agg + top-K mask (one block per graph, 1024 thr) ------
// one node per thread; top-K knockout via wave shfl_xor argmax + 16-entry combine.
__global__ __launch_bounds__(1024) void smask_k(const float* __restrict__ z,
                                                const unsigned short* __restrict__ col16,
                                                const int* __restrict__ cnt,
                                                const float* __restrict__ b3,
                                                float* __restrict__ out) {
    __shared__ float sz[1024];
    __shared__ float sl[1024];
    __shared__ float slo[1024];
    __shared__ float rv[16];
    __shared__ int   ri[16];
    __shared__ float sth;
    int g = blockIdx.x, t = threadIdx.x;
    int wv = t >> 6, ln = t & 63;
    int base = g << 10;
    sz[t] = z[base + t];
    __syncthreads();
    float bb = b3[0];
    {
        int gv = base + t;
        int n = cnt[gv];
        float dv = rsqrtf((float)n + 1.0f);
        float acc = sz[t];
        const unsigned short* ip = col16 + gv;   // slot-major, coalesced
        int j = 0;
        for (; j + 2 <= n; j += 2)
            acc += sz[ip[(size_t)j * NTOT]] + sz[ip[(size_t)(j + 1) * NTOT]];
        for (; j < n; ++j) acc += sz[ip[(size_t)j * NTOT]];
        float lg = acc * dv + bb;
        sl[t] = lg; slo[t] = lg;
    }
    __syncthreads();
    for (int pass = 0; pass < KSEL; ++pass) {
        float bv = sl[t];
        int bi = t;
#pragma unroll
        for (int off = 32; off; off >>= 1) {   // wave argmax, deterministic tie-break
            float ov = __shfl_xor(bv, off);
            int   oi = __shfl_xor(bi, off);
            if (ov > bv || (ov == bv && oi < bi)) { bv = ov; bi = oi; }
        }
        if (ln == 0) { rv[wv] = bv; ri[wv] = bi; }
        __syncthreads();
        if (t == 0) {
            float mv = rv[0]; int mi = ri[0];
#pragma unroll
            for (int q = 1; q < 16; ++q)
                if (rv[q] > mv || (rv[q] == mv && ri[q] < mi)) { mv = rv[q]; mi = ri[q]; }
            sth = mv; sl[mi] = -INFINITY;
        }
        __syncthreads();
    }
    float th = sth;
    out[base + t] = (slo[t] >= th) ? 1.f : 0.f;
}

// =====================================================================================
extern "C" void kernel_launch(void* const* d_in, const int* in_sizes, int n_in,
                              void* d_out, int out_size, void* d_ws, size_t ws_size,
                              hipStream_t stream) {
    const float* x        = (const float*)d_in[0];
    const int*   edge_src = (const int*)d_in[1];
    const int*   edge_dst = (const int*)d_in[2];
    const float* W0 = (const float*)d_in[4];
    const float* b0 = (const float*)d_in[5];
    const float* W1 = (const float*)d_in[6];
    const float* b1 = (const float*)d_in[7];
    const float* Wf = (const float*)d_in[8];
    const float* bf = (const float*)d_in[9];
    const float* W2 = (const float*)d_in[10];
    const float* b2 = (const float*)d_in[11];
    const float* W3 = (const float*)d_in[12];
    const float* b3 = (const float*)d_in[13];
    float* out = (float*)d_out;

    char* w = (char*)d_ws;
    int*            cnt   = (int*)w;            w += (size_t)NTOT * 4;
    unsigned short* col16 = (unsigned short*)w; w += (size_t)NTOT * MAXDEG * 2;
    float*          fvec  = (float*)w;          w += (size_t)NTOT * 4;
    unsigned short* Ah    = (unsigned short*)w; w += (size_t)NTOT * 128 * 2;  // A hi
    unsigned short* Al    = (unsigned short*)w; w += (size_t)NTOT * 128 * 2;  // A lo
    float*          Q     = (float*)w;          w += (size_t)NTOT * 128 * 4;  // Z
    float*          part  = (float*)w;          w += (size_t)NB * 128 * 4;
    float*          gproj = (float*)w;          w += (size_t)NB * 128 * 4;
    float*          z     = (float*)w;          w += (size_t)NTOT * 4;
    unsigned short* Wph   = (unsigned short*)w; w += (size_t)320 * 128 * 2;   // packed W hi
    unsigned short* Wpl   = (unsigned short*)w; w += (size_t)320 * 128 * 2;   // packed W lo

    // csr (per-graph, LDS atomics; slot-major col16) + pack + part-zero, one dispatch
    csrpack_k<<<NB + 41, 1024, 0, stream>>>(edge_src, edge_dst, cnt, col16,
                                            W0, W1, W2, Wph, Wpl, part);

    // conv0: A = agg(x) [K=64]; Z0 = relu(A@W0+b0)*dinv, fused maxpool -> part
    agg_k<<<NB * 4, 1024, 0, stream>>>(nullptr, x, col16, cnt, Ah, Al, 2, nullptr,
                                       nullptr, nullptr, nullptr, nullptr, nullptr);
    gemm_k<<<NTOT / 64, 256, 0, stream>>>(Ah, Al, Wph, Wpl, b0, Q, FEAT,
                                          nullptr, nullptr, part, nullptr, cnt, nullptr);

    // conv1 twice (same weights); first agg also carries the NB glob blocks
    agg_k<<<NB * 8 + NB, 1024, 0, stream>>>(Q, nullptr, col16, cnt, Ah, Al, 3, nullptr,
                                            Wf, bf, W2, gproj, part);
    gemm_k<<<NTOT / 64, 256, 0, stream>>>(Ah, Al, Wph + 64 * 128, Wpl + 64 * 128, b1, Q,
                                          HID, nullptr, nullptr, nullptr, nullptr, cnt,
                                          nullptr);
    agg_k<<<NB * 8, 1024, 0, stream>>>(Q, nullptr, col16, cnt, Ah, Al, 3, nullptr,
                                       nullptr, nullptr, nullptr, nullptr, nullptr);
    gemm_k<<<NTOT / 64, 256, 0, stream>>>(Ah, Al, Wph + 64 * 128, Wpl + 64 * 128, b1, Q,
                                          HID, nullptr, nullptr, nullptr, nullptr, cnt,
                                          nullptr);

    // conv2: A = agg(Z2) (+fvec); z = dinv*(relu(A@W2a + f*gproj + b2)@W3)
    agg_k<<<NB * 8, 1024, 0, stream>>>(Q, nullptr, col16, cnt, Ah, Al, 3, fvec,
                                       nullptr, nullptr, nullptr, nullptr, nullptr);
    gemm_k<<<NTOT / 64, 256, 0, stream>>>(Ah, Al, Wph + 192 * 128, Wpl + 192 * 128, b2,
                                          nullptr, HID, fvec, gproj, nullptr, W3, cnt, z);

    // logits = agg_scalar(z) + b3, then per-graph top-10 mask (fused)
    smask_k<<<NB, 1024, 0, stream>>>(z, col16, cnt, b3, out);
}